// Round 10
// baseline (574.468 us; speedup 1.0000x reference)
//
#include <hip/hip_runtime.h>

// TopKGate: x[16384,2048] fp32, Wg[2048,64] fp32 ->
//   gate_weights[T,64], top_idx[T,2] (as float), aux_loss (1 float)
//
// Dual-path dataflow: x via per-lane VMEM (distance-2 register prefetch,
// L1 return path), w via per-wave private LDS chunks staged with
// global_load_lds + counted vmcnt (LDS return path). No barriers in main loop.
// Block: 4 waves, 32 tokens, K-split 4. Lane tile 4 tok x 8 exp.

constexpr int DD = 2048;
constexpr int EE = 64;
constexpr int MTOK = 32;              // tokens per block (each wave covers all)
constexpr int KSPLIT = 4;             // waves per block, K-split
constexpr int KSLICE = DD / KSPLIT;   // 512
constexpr int BK = 32;                // w chunk (k's) staged in LDS
constexpr int NCHK = KSLICE / BK;     // 16 chunks per wave

__global__ void __attribute__((amdgpu_flat_work_group_size(256, 256),
                               amdgpu_waves_per_eu(2, 2)))
gate_kernel(
    const float* __restrict__ x, const float* __restrict__ Wg,
    float* __restrict__ gate_out, float* __restrict__ idx_out,
    float* __restrict__ pSum, float* __restrict__ pCnt)
{
    __shared__ __align__(16) float wlds[KSPLIT * 2 * BK * EE];  // 64 KB
    __shared__ float auxsm[2][KSPLIT][64];                      // 2 KB

    const int tid  = threadIdx.x;
    const int wv   = tid >> 6;          // 0..3 (K-slice)
    const int lane = tid & 63;
    const int tg   = lane >> 3;         // token group 0..7
    const int eg   = lane & 7;          // expert group 0..7
    const size_t tok0 = (size_t)blockIdx.x * MTOK;
    const int kbase = wv * KSLICE;

    float* wbase = &wlds[wv * 2 * BK * EE];   // per-wave private 2 x 8 KB

    // stage one contiguous 8 KB Wg chunk into LDS buffer buf (8 x 16B per lane)
    auto stage = [&](int buf, int ck) {
        const float* wsrc = Wg + (size_t)(kbase + ck * BK) * EE;
        float* wdst = wbase + buf * (BK * EE);
#pragma unroll
        for (int r = 0; r < 8; ++r) {
            int s = lane + r * 64;   // float4 slot, linear
            __builtin_amdgcn_global_load_lds(wsrc + s * 4, wdst + s * 4, 16, 0, 0);
        }
    };

    float acc[4][8];
#pragma unroll
    for (int i = 0; i < 4; ++i)
#pragma unroll
        for (int j = 0; j < 8; ++j) acc[i][j] = 0.f;

    float4 xq[4][4];   // [buf][row]: x quad pipeline, distance-2
    const float* xr[4];
#pragma unroll
    for (int i = 0; i < 4; ++i)
        xr[i] = x + (tok0 + tg * 4 + i) * DD + kbase;

    stage(0, 0);
    stage(1, 1);
    // wait for stage(0): exactly stage(1)'s 8 loads are newer
    asm volatile("s_waitcnt vmcnt(8)" ::: "memory");
    __builtin_amdgcn_sched_barrier(0);

    // x prologue: quads 0,1
#pragma unroll
    for (int i = 0; i < 4; ++i) xq[0][i] = *(const float4*)(xr[i] + 0);
#pragma unroll
    for (int i = 0; i < 4; ++i) xq[1][i] = *(const float4*)(xr[i] + 4);

    // one quad: optionally prefetch x quad (c*8+q+2); 8 w ds_reads; 128 FMAs
#define QUAD(c, q, PFX)                                                        \
    do {                                                                       \
        if (PFX) {                                                             \
            _Pragma("unroll")                                                  \
            for (int i = 0; i < 4; ++i)                                        \
                xq[((q) + 2) & 3][i] =                                         \
                    *(const float4*)(xr[i] + (c) * BK + ((q) + 2) * 4);        \
        }                                                                      \
        const float* wb = wbase + ((c) & 1) * (BK * EE) + (q) * 4 * EE;        \
        _Pragma("unroll")                                                      \
        for (int kk = 0; kk < 4; ++kk) {                                       \
            float4 wA = *(const float4*)&wb[kk * EE + eg * 8];                 \
            float4 wB = *(const float4*)&wb[kk * EE + eg * 8 + 4];             \
            _Pragma("unroll")                                                  \
            for (int i = 0; i < 4; ++i) {                                      \
                const float xs = ((const float*)&xq[(q) & 3][i])[kk];          \
                acc[i][0] = fmaf(xs, wA.x, acc[i][0]);                         \
                acc[i][1] = fmaf(xs, wA.y, acc[i][1]);                         \
                acc[i][2] = fmaf(xs, wA.z, acc[i][2]);                         \
                acc[i][3] = fmaf(xs, wA.w, acc[i][3]);                         \
                acc[i][4] = fmaf(xs, wB.x, acc[i][4]);                         \
                acc[i][5] = fmaf(xs, wB.y, acc[i][5]);                         \
                acc[i][6] = fmaf(xs, wB.z, acc[i][6]);                         \
                acc[i][7] = fmaf(xs, wB.w, acc[i][7]);                         \
            }                                                                  \
        }                                                                      \
    } while (0)

#pragma unroll 1
    for (int c = 0; c < NCHK; ++c) {
        if (c >= 1) {
            if (c + 1 < NCHK) stage((c + 1) & 1, c + 1);
            // stage(c) drained: >=40 ops (chunk c-1 x + stage(c+1)) are newer
            asm volatile("s_waitcnt vmcnt(16)" ::: "memory");
            __builtin_amdgcn_sched_barrier(0);
        }
        const bool last = (c == NCHK - 1);
        QUAD(c, 0, 1);
        QUAD(c, 1, 1);
        QUAD(c, 2, 1);
        QUAD(c, 3, 1);
        QUAD(c, 4, 1);
        QUAD(c, 5, 1);
        QUAD(c, 6, !last);
        QUAD(c, 7, !last);
    }
#undef QUAD

    // ---- combine K-partials: red aliases wlds (all reads done -> barrier) ----
    __syncthreads();
    float (*red)[MTOK][68] = (float (*)[MTOK][68]) & wlds[0];  // 34.8 KB <= 64 KB
#pragma unroll
    for (int i = 0; i < 4; ++i) {
        float4 lo = make_float4(acc[i][0], acc[i][1], acc[i][2], acc[i][3]);
        float4 hi = make_float4(acc[i][4], acc[i][5], acc[i][6], acc[i][7]);
        *(float4*)&red[wv][tg * 4 + i][eg * 8]     = lo;
        *(float4*)&red[wv][tg * 4 + i][eg * 8 + 4] = hi;
    }
    __syncthreads();

    // ---- epilogue: wave wv handles tokens [wv*8, wv*8+8); lane = expert ----
    float sumP_acc = 0.f;
    float cnt_acc  = 0.f;
#pragma unroll 1
    for (int tt = 0; tt < 8; ++tt) {
        const int tl = wv * 8 + tt;
        const size_t t = tok0 + tl;
        float v = red[0][tl][lane] + red[1][tl][lane]
                + red[2][tl][lane] + red[3][tl][lane];

        float m = v;
#pragma unroll
        for (int off = 32; off; off >>= 1) m = fmaxf(m, __shfl_xor(m, off, 64));
        float p = expf(v - m);
        float s = p;
#pragma unroll
        for (int off = 32; off; off >>= 1) s += __shfl_xor(s, off, 64);
        float prob = p / s;
        sumP_acc += prob;

        // top-1 (ties -> lowest index, matches lax.top_k)
        float bv = prob; int bi = lane;
#pragma unroll
        for (int off = 32; off; off >>= 1) {
            float ov = __shfl_xor(bv, off, 64);
            int   oi = __shfl_xor(bi, off, 64);
            if (ov > bv || (ov == bv && oi < bi)) { bv = ov; bi = oi; }
        }
        // top-2
        float v2 = (lane == bi) ? -1.f : prob;
        float bv2 = v2; int bi2 = lane;
#pragma unroll
        for (int off = 32; off; off >>= 1) {
            float ov = __shfl_xor(bv2, off, 64);
            int   oi = __shfl_xor(bi2, off, 64);
            if (ov > bv2 || (ov == bv2 && oi < bi2)) { bv2 = ov; bi2 = oi; }
        }

        float denom = bv + bv2;
        float g1 = bv / denom, g2 = bv2 / denom;
        float g = (lane == bi) ? g1 : ((lane == bi2) ? g2 : 0.f);
        gate_out[t * EE + lane] = g;
        if (lane == 0) {
            idx_out[2 * t]     = (float)bi;
            idx_out[2 * t + 1] = (float)bi2;
        }
        cnt_acc += (lane == bi)  ? 1.f : 0.f;
        cnt_acc += (lane == bi2) ? 1.f : 0.f;
    }

    // ---- per-block aux partials (deterministic) ----
    auxsm[0][wv][lane] = sumP_acc;
    auxsm[1][wv][lane] = cnt_acc;
    __syncthreads();
    if (wv == 0) {
        float sp = 0.f, c2 = 0.f;
#pragma unroll
        for (int w = 0; w < KSPLIT; ++w) {
            sp += auxsm[0][w][lane];
            c2 += auxsm[1][w][lane];
        }
        pSum[(size_t)blockIdx.x * 64 + lane] = sp;
        pCnt[(size_t)blockIdx.x * 64 + lane] = c2;
    }
}

// parallel aux reduction: 1024 threads (16 waves), 4-deep ILP + LDS reduce
__global__ __launch_bounds__(1024) void aux_kernel(
    const float* __restrict__ pSum, const float* __restrict__ pCnt,
    float* __restrict__ aux_out, int nblocks, float scale)
{
    const int tid  = threadIdx.x;
    const int wv   = tid >> 6;       // 0..15
    const int lane = tid & 63;       // = expert id
    __shared__ float smem[2][16][64];

    float sp[4] = {0.f, 0.f, 0.f, 0.f};
    float cc[4] = {0.f, 0.f, 0.f, 0.f};
    for (int b = wv * 4; b < nblocks; b += 64) {
#pragma unroll
        for (int u = 0; u < 4; ++u) {
            sp[u] += pSum[(size_t)(b + u) * 64 + lane];
            cc[u] += pCnt[(size_t)(b + u) * 64 + lane];
        }
    }
    smem[0][wv][lane] = (sp[0] + sp[1]) + (sp[2] + sp[3]);
    smem[1][wv][lane] = (cc[0] + cc[1]) + (cc[2] + cc[3]);
    __syncthreads();
    if (wv == 0) {
        float SP = 0.f, C = 0.f;
#pragma unroll
        for (int w = 0; w < 16; ++w) {
            SP += smem[0][w][lane];
            C  += smem[1][w][lane];
        }
        float prod = SP * C;
#pragma unroll
        for (int off = 32; off; off >>= 1) prod += __shfl_xor(prod, off, 64);
        if (lane == 0) aux_out[0] = prod * scale;
    }
}

extern "C" void kernel_launch(void* const* d_in, const int* in_sizes, int n_in,
                              void* d_out, int out_size, void* d_ws, size_t ws_size,
                              hipStream_t stream) {
    const float* x  = (const float*)d_in[0];
    const float* Wg = (const float*)d_in[1];
    const int T = in_sizes[0] / DD;          // 16384

    float* out      = (float*)d_out;
    float* gate_out = out;                                // T*64
    float* idx_out  = out + (size_t)T * EE;               // T*2 (as float)
    float* aux_out  = idx_out + (size_t)T * 2;            // 1

    const int nblocks = T / MTOK;                         // 512
    float* pSum = (float*)d_ws;                           // nblocks*64
    float* pCnt = pSum + (size_t)nblocks * 64;            // nblocks*64

    gate_kernel<<<nblocks, 256, 0, stream>>>(x, Wg, gate_out, idx_out, pSum, pCnt);

    const float scale = (float)EE / ((float)T * (float)T);
    aux_kernel<<<1, 1024, 0, stream>>>(pSum, pCnt, aux_out, nblocks, scale);
}

// Round 11
// 86.933 us; speedup vs baseline: 6.6081x; 6.6081x over previous
//
#include <hip/hip_runtime.h>

// TopKGate via split-precision f16 MFMA (no fp32 MFMA on CDNA4):
//   x = xh + xl/4096, w = wh + wl/4096 (f16 planes, lo pre-scaled x4096)
//   logits = xh*wh + (xh*wl' + xl'*wh)/4096   (xl*wl ~2^-22 rel, negligible)
// Pre-kernel: Wg [2048][64] fp32 -> whT/wlT [64][2048] f16, transposed +
//   XOR-swizzled within 128B chunks (so MFMA B-frag ds_reads are conflict-lite).
// Main: 256 blocks x 4 waves, BM=64 tok, full E=64. Wave (mh,nh) owns a 32x32
//   output quadrant, mfma_f32_32x32x16_f16, double-buffered x staging via
//   global_load_lds (linear dest + source-XOR swizzle), 1 barrier/chunk.

typedef __attribute__((ext_vector_type(8))) _Float16 half8;
typedef __attribute__((ext_vector_type(16))) float f32x16;

constexpr int DD = 2048;
constexpr int EE = 64;
constexpr int BM = 64;          // tokens per block
constexpr int BK = 64;          // k per staged chunk
constexpr int NCH = DD / BK;    // 32 chunks

// ---- pre-kernel: split + transpose + swizzle Wg into ws ----
__global__ __launch_bounds__(256) void wsplit_kernel(
    const float* __restrict__ Wg, _Float16* __restrict__ whT,
    _Float16* __restrict__ wlT)
{
    const int k = blockIdx.x * 256 + threadIdx.x;    // 0..2047
    float wrow[64];
    const float4* src = (const float4*)(Wg + (size_t)k * EE);
#pragma unroll
    for (int q = 0; q < 16; ++q) ((float4*)wrow)[q] = src[q];
    const int kc = k >> 6, kl = k & 63;
#pragma unroll
    for (int n = 0; n < 64; ++n) {
        float v = wrow[n];
        _Float16 h = (_Float16)v;
        _Float16 l = (_Float16)((v - (float)h) * 4096.f);
        size_t idx = (size_t)n * DD + kc * 64 + (kl ^ ((n & 7) << 3));
        whT[idx] = h;
        wlT[idx] = l;
    }
}

__global__ __launch_bounds__(256, 1) void gate_kernel(
    const float* __restrict__ x, const _Float16* __restrict__ whT,
    const _Float16* __restrict__ wlT,
    float* __restrict__ gate_out, float* __restrict__ idx_out,
    float* __restrict__ pSum, float* __restrict__ pCnt)
{
    __shared__ __align__(16) union {
        struct { float xs[2][BM][BK]; _Float16 wsb[2][2][64][BK]; } st; // 64 KB
        struct { float logits[BM][68]; float auxsm[2][4][64]; } ep;    // 19.5 KB
    } sm;

    const int tid  = threadIdx.x;
    const int wv   = tid >> 6;
    const int lane = tid & 63;
    const int mh   = wv & 1;            // token-half of output
    const int nh   = wv >> 1;           // expert-half of output
    const size_t tok0 = (size_t)blockIdx.x * BM;

    // stage chunk c into buffer buf: x (16 KB, HBM) + w planes (16 KB, L2)
    auto stage = [&](int buf, int c) {
        const float* xg = x + tok0 * DD + c * BK;
#pragma unroll
        for (int r = 0; r < 4; ++r) {
            int slot = tid + r * 256;            // float4 slot (linear dest)
            int row  = slot >> 4;
            int cb   = (slot & 15) << 4;         // byte within 256B row
            int sb   = cb ^ ((row & 7) << 5);    // source-swizzled byte
            __builtin_amdgcn_global_load_lds(
                xg + (size_t)row * DD + (sb >> 2),
                &sm.st.xs[buf][row][(slot & 15) << 2], 16, 0, 0);
        }
#pragma unroll
        for (int p = 0; p < 2; ++p) {
            const _Float16* wg = (p ? wlT : whT) + c * BK;
#pragma unroll
            for (int r = 0; r < 2; ++r) {
                int slot = tid + r * 256;        // 16B slot (8 halves)
                int n = slot >> 3, j = slot & 7;
                __builtin_amdgcn_global_load_lds(
                    wg + (size_t)n * DD + j * 8,
                    &sm.st.wsb[buf][p][n][j * 8], 16, 0, 0);
            }
        }
    };

    f32x16 acc1, acc2;
#pragma unroll
    for (int e = 0; e < 16; ++e) { acc1[e] = 0.f; acc2[e] = 0.f; }

    const int arow = mh * 32 + (lane & 31);      // A row (token within tile)
    const int brow = nh * 32 + (lane & 31);      // B row (expert)
    const int kg   = lane >> 5;                  // k-group (same map for A & B)
    const int asw  = (arow & 7) << 3;            // x swizzle (float units)
    const int bsw  = (brow & 7) << 3;            // w swizzle (f16 units)

    stage(0, 0);
    stage(1, 1);
    __syncthreads();

#pragma unroll 1
    for (int c = 0; c < NCH; ++c) {
        const int buf = c & 1;
#pragma unroll
        for (int kk = 0; kk < 4; ++kk) {
            const int f0 = kk * 16 + kg * 8;
            float4 xa = *(const float4*)&sm.st.xs[buf][arow][(f0)     ^ asw];
            float4 xb = *(const float4*)&sm.st.xs[buf][arow][(f0 + 4) ^ asw];
            float xv0 = xa.x, xv1 = xa.y, xv2 = xa.z, xv3 = xa.w;
            float xv4 = xb.x, xv5 = xb.y, xv6 = xb.z, xv7 = xb.w;
            half8 ah, al;
#define CVT(E, V)                                                              \
            { _Float16 h = (_Float16)(V); ah[E] = h;                           \
              al[E] = (_Float16)(((V) - (float)h) * 4096.f); }
            CVT(0, xv0) CVT(1, xv1) CVT(2, xv2) CVT(3, xv3)
            CVT(4, xv4) CVT(5, xv5) CVT(6, xv6) CVT(7, xv7)
#undef CVT
            half8 bh = *(const half8*)&sm.st.wsb[buf][0][brow][f0 ^ bsw];
            half8 bl = *(const half8*)&sm.st.wsb[buf][1][brow][f0 ^ bsw];
            acc1 = __builtin_amdgcn_mfma_f32_32x32x16_f16(ah, bh, acc1, 0, 0, 0);
            acc2 = __builtin_amdgcn_mfma_f32_32x32x16_f16(ah, bl, acc2, 0, 0, 0);
            acc2 = __builtin_amdgcn_mfma_f32_32x32x16_f16(al, bh, acc2, 0, 0, 0);
        }
        __syncthreads();                          // all waves done with buf
        if (c + 2 < NCH) stage(buf, c + 2);       // refill consumed buffer
    }

    // ---- D -> logits LDS (verified m74/m101 layout), combine planes ----
    const float inv = 1.f / 4096.f;
#pragma unroll
    for (int e = 0; e < 16; ++e) {
        int lr = mh * 32 + (e & 3) + ((e >> 2) << 3) + ((lane >> 5) << 2);
        int lc = nh * 32 + (lane & 31);
        sm.ep.logits[lr][lc] = acc1[e] + acc2[e] * inv;
    }
    __syncthreads();

    // ---- epilogue: wave wv -> tokens [wv*16, wv*16+16); lane = expert ----
    float sumP_acc = 0.f;
    float cnt_acc  = 0.f;
#pragma unroll 1
    for (int tt = 0; tt < 16; ++tt) {
        const int tl = wv * 16 + tt;
        const size_t t = tok0 + tl;
        float v = sm.ep.logits[tl][lane];

        float m = v;
#pragma unroll
        for (int off = 32; off; off >>= 1) m = fmaxf(m, __shfl_xor(m, off, 64));
        float p = expf(v - m);
        float s = p;
#pragma unroll
        for (int off = 32; off; off >>= 1) s += __shfl_xor(s, off, 64);
        float prob = p / s;
        sumP_acc += prob;

        // top-1 (ties -> lowest index, matches lax.top_k)
        float bv = prob; int bi = lane;
#pragma unroll
        for (int off = 32; off; off >>= 1) {
            float ov = __shfl_xor(bv, off, 64);
            int   oi = __shfl_xor(bi, off, 64);
            if (ov > bv || (ov == bv && oi < bi)) { bv = ov; bi = oi; }
        }
        // top-2
        float v2 = (lane == bi) ? -1.f : prob;
        float bv2 = v2; int bi2 = lane;
#pragma unroll
        for (int off = 32; off; off >>= 1) {
            float ov = __shfl_xor(bv2, off, 64);
            int   oi = __shfl_xor(bi2, off, 64);
            if (ov > bv2 || (ov == bv2 && oi < bi2)) { bv2 = ov; bi2 = oi; }
        }

        float denom = bv + bv2;
        float g1 = bv / denom, g2 = bv2 / denom;
        float g = (lane == bi) ? g1 : ((lane == bi2) ? g2 : 0.f);
        gate_out[t * EE + lane] = g;
        if (lane == 0) {
            idx_out[2 * t]     = (float)bi;
            idx_out[2 * t + 1] = (float)bi2;
        }
        cnt_acc += (lane == bi)  ? 1.f : 0.f;
        cnt_acc += (lane == bi2) ? 1.f : 0.f;
    }

    // ---- per-block aux partials (deterministic) ----
    sm.ep.auxsm[0][wv][lane] = sumP_acc;
    sm.ep.auxsm[1][wv][lane] = cnt_acc;
    __syncthreads();
    if (wv == 0) {
        float sp = 0.f, c2 = 0.f;
#pragma unroll
        for (int w = 0; w < 4; ++w) {
            sp += sm.ep.auxsm[0][w][lane];
            c2 += sm.ep.auxsm[1][w][lane];
        }
        pSum[(size_t)blockIdx.x * 64 + lane] = sp;
        pCnt[(size_t)blockIdx.x * 64 + lane] = c2;
    }
}

// parallel aux reduction: 1024 threads (16 waves), 4-deep ILP + LDS reduce
__global__ __launch_bounds__(1024) void aux_kernel(
    const float* __restrict__ pSum, const float* __restrict__ pCnt,
    float* __restrict__ aux_out, int nblocks, float scale)
{
    const int tid  = threadIdx.x;
    const int wv   = tid >> 6;       // 0..15
    const int lane = tid & 63;       // = expert id
    __shared__ float smem[2][16][64];

    float sp[4] = {0.f, 0.f, 0.f, 0.f};
    float cc[4] = {0.f, 0.f, 0.f, 0.f};
    for (int b = wv * 4; b < nblocks; b += 64) {
#pragma unroll
        for (int u = 0; u < 4; ++u) {
            sp[u] += pSum[(size_t)(b + u) * 64 + lane];
            cc[u] += pCnt[(size_t)(b + u) * 64 + lane];
        }
    }
    smem[0][wv][lane] = (sp[0] + sp[1]) + (sp[2] + sp[3]);
    smem[1][wv][lane] = (cc[0] + cc[1]) + (cc[2] + cc[3]);
    __syncthreads();
    if (wv == 0) {
        float SP = 0.f, C = 0.f;
#pragma unroll
        for (int w = 0; w < 16; ++w) {
            SP += smem[0][w][lane];
            C  += smem[1][w][lane];
        }
        float prod = SP * C;
#pragma unroll
        for (int off = 32; off; off >>= 1) prod += __shfl_xor(prod, off, 64);
        if (lane == 0) aux_out[0] = prod * scale;
    }
}

extern "C" void kernel_launch(void* const* d_in, const int* in_sizes, int n_in,
                              void* d_out, int out_size, void* d_ws, size_t ws_size,
                              hipStream_t stream) {
    const float* x  = (const float*)d_in[0];
    const float* Wg = (const float*)d_in[1];
    const int T = in_sizes[0] / DD;          // 16384

    float* out      = (float*)d_out;
    float* gate_out = out;                                // T*64
    float* idx_out  = out + (size_t)T * EE;               // T*2 (as float)
    float* aux_out  = idx_out + (size_t)T * 2;            // 1

    const int nblocks = T / BM;                           // 256
    _Float16* whT = (_Float16*)d_ws;                      // 64*2048 f16 = 256 KB
    _Float16* wlT = whT + (size_t)EE * DD;                // 256 KB
    float* pSum = (float*)(wlT + (size_t)EE * DD);        // nblocks*64
    float* pCnt = pSum + (size_t)nblocks * 64;            // nblocks*64

    wsplit_kernel<<<DD / 256, 256, 0, stream>>>(Wg, whT, wlT);
    gate_kernel<<<nblocks, 256, 0, stream>>>(x, whT, wlT,
                                             gate_out, idx_out, pSum, pCnt);

    const float scale = (float)EE / ((float)T * (float)T);
    aux_kernel<<<1, 1024, 0, stream>>>(pSum, pCnt, aux_out, nblocks, scale);
}